// Round 7
// baseline (958.540 us; speedup 1.0000x reference)
//
#include <hip/hip_runtime.h>
#include <hip/hip_bf16.h>

typedef __attribute__((ext_vector_type(8))) short bf16x8;
typedef __attribute__((ext_vector_type(4))) float f32x4;
typedef __attribute__((ext_vector_type(4))) unsigned int u32x4;

#define HH 512
#define WWD 512
#define HW (HH * WWD)
#define TW 64
#define HALO_W 66
#define ROWS 10                 // circular slots: 6 read + 4 write, disjoint
#define NPIX (ROWS * HALO_W)    // 660
#define XBYTES (NPIX * 64)      // 42240
#define DUMMY XBYTES            // 1KB scratch for padded-decode dummy writes
#define NITER 32                // 32 * 4 = 128 rows per block

__device__ __forceinline__ unsigned short f2bf(float f) {
    unsigned u = __builtin_bit_cast(unsigned, f);
    u += 0x7FFFu + ((u >> 16) & 1u);
    return (unsigned short)(u >> 16);
}

// steady-state tile: 1088 units = (g:4) x (hh:4) x (ww:68), real ww<66.
// threads 0..511 take u=tid, u=tid+512; wave 0 also takes u=1024+lane.
__device__ __forceinline__ void issue4(const float* __restrict__ xb, int row0, int w0,
                                       float (&sv)[3][8]) {
    #pragma unroll
    for (int k = 0; k < 3; ++k) {
        if (k == 2 && threadIdx.x >= 64) continue;
        int u = (k < 2) ? (int)threadIdx.x + k * 512 : 1024 + (int)(threadIdx.x & 63);
        int g = u / 272, r = u - g * 272, hh = r / 68, ww = r - hh * 68;
        int wwc = ww < 66 ? ww : 65;
        int row = row0 + hh, cl = w0 + wwc - 1;
        bool ok = (ww < 66) & ((unsigned)row < 512u) & ((unsigned)cl < 512u);
        int rowc = row < 0 ? 0 : (row > 511 ? 511 : row);
        int clc  = cl  < 0 ? 0 : (cl  > 511 ? 511 : cl);
        const float* src = xb + (size_t)(g * 8) * HW + rowc * WWD + clc;
        #pragma unroll
        for (int j = 0; j < 8; ++j) { float v = src[(size_t)j * HW]; sv[k][j] = ok ? v : 0.f; }
    }
}

__device__ __forceinline__ void write4(char* smem, int wsb, float (&sv)[3][8]) {
    #pragma unroll
    for (int k = 0; k < 3; ++k) {
        if (k == 2 && threadIdx.x >= 64) continue;
        int u = (k < 2) ? (int)threadIdx.x + k * 512 : 1024 + (int)(threadIdx.x & 63);
        int g = u / 272, r = u - g * 272, hh = r / 68, ww = r - hh * 68;
        int slot = wsb + hh; if (slot >= ROWS) slot -= ROWS;
        int byte = (ww < 66) ? (g * NPIX + slot * HALO_W + ww) * 16
                             : (DUMMY + (threadIdx.x & 63) * 16);
        unsigned q0 = (unsigned)f2bf(sv[k][0]) | ((unsigned)f2bf(sv[k][1]) << 16);
        unsigned q1 = (unsigned)f2bf(sv[k][2]) | ((unsigned)f2bf(sv[k][3]) << 16);
        unsigned q2 = (unsigned)f2bf(sv[k][4]) | ((unsigned)f2bf(sv[k][5]) << 16);
        unsigned q3 = (unsigned)f2bf(sv[k][6]) | ((unsigned)f2bf(sv[k][7]) << 16);
        u32x4 q = { q0, q1, q2, q3 };
        *(u32x4*)(smem + byte) = q;
    }
}

template<bool WR, bool ISS, bool BAR>
__device__ __forceinline__ void conv_body(char* smem, const float* __restrict__ xb,
                                          float* __restrict__ ob, bf16x8 (&wf)[9][2],
                                          float (&cur)[3][8], float (&nxt)[3][8],
                                          int srb, int rowbase, int issrow, int w0,
                                          int wv, int col16, int g4) {
    if (WR) {
        // 4 newest outstanding vmem ops = previous iter's stores; everything
        // older (cur's loads) must have landed before we repack cur -> LDS.
        asm volatile("s_waitcnt vmcnt(4)" ::: "memory");
        __builtin_amdgcn_sched_barrier(0);
        int wsb = srb + 6; if (wsb >= ROWS) wsb -= ROWS;
        write4(smem, wsb, cur);
    }
    if (ISS) issue4(xb, issrow, w0, nxt);   // lands during next iter's compute

    f32x4 acc[2][2];
    {
        f32x4 z = {0.f, 0.f, 0.f, 0.f};
        acc[0][0] = z; acc[0][1] = z; acc[1][0] = z; acc[1][1] = z;
    }
    int rs[3];
    #pragma unroll
    for (int dh = 0; dh < 3; ++dh) {
        int s = srb + (wv >> 1) + dh; if (s >= ROWS) s -= ROWS;
        rs[dh] = s * HALO_W;
    }
    const int wcb = (wv & 1) * 32;
    const char* xg = smem + g4 * (NPIX * 16);
    #pragma unroll
    for (int dh = 0; dh < 3; ++dh) {
        #pragma unroll
        for (int dw = 0; dw < 3; ++dw) {
            const int tap = dh * 3 + dw;
            #pragma unroll
            for (int m = 0; m < 2; ++m) {
                bf16x8 a = *(const bf16x8*)(xg + (rs[dh] + wcb + m * 16 + col16 + dw) * 16);
                acc[m][0] = __builtin_amdgcn_mfma_f32_16x16x32_bf16(a, wf[tap][0], acc[m][0], 0, 0, 0);
                acc[m][1] = __builtin_amdgcn_mfma_f32_16x16x32_bf16(a, wf[tap][1], acc[m][1], 0, 0, 0);
            }
        }
    }
    {
        float* orow = ob + (size_t)(rowbase + (wv >> 1)) * WWD + w0 + wcb;
        #pragma unroll
        for (int m = 0; m < 2; ++m)
            #pragma unroll
            for (int n = 0; n < 2; ++n)
                *(f32x4*)(orow + (size_t)(n * 16 + col16) * HW + m * 16 + g4 * 4) = acc[m][n];
    }
    if (BAR) {
        asm volatile("s_waitcnt lgkmcnt(0)" ::: "memory");
        __builtin_amdgcn_sched_barrier(0);
        __builtin_amdgcn_s_barrier();
        __builtin_amdgcn_sched_barrier(0);
    }
}

__global__ __launch_bounds__(512, 4)
void conv3x3_mfma(const float* __restrict__ x,
                  const float* __restrict__ wk,
                  float* __restrict__ out) {
    __shared__ __align__(16) char smem[XBYTES + 1024];   // 43264 B -> 2 blocks/CU

    const int tid   = threadIdx.x;
    const int lane  = tid & 63;
    const int wv    = tid >> 6;
    const int col16 = lane & 15;
    const int g4    = lane >> 4;

    const int w0    = blockIdx.x * TW;
    const int hbase = blockIdx.y * (4 * NITER);
    const int b     = blockIdx.z;

    const float* xb = x + (size_t)b * 32 * HW;
    float* ob = out + (size_t)b * 32 * HW;

    // ---- weights: stage f32 into x-LDS scratch, gather to 72 VGPRs ----
    bf16x8 wf[9][2];
    {
        float* ws = (float*)smem;
        for (int i = tid; i < 9216; i += 512) {
            int oc = i / 288;
            ws[oc * 289 + (i - oc * 288)] = wk[i];
        }
        __syncthreads();
        #pragma unroll
        for (int tap = 0; tap < 9; ++tap) {
            #pragma unroll
            for (int n = 0; n < 2; ++n) {
                bf16x8 f;
                #pragma unroll
                for (int j = 0; j < 8; ++j)
                    f[j] = (short)f2bf(ws[(n * 16 + col16) * 289 + (g4 * 8 + j) * 9 + tap]);
                wf[tap][n] = f;
            }
        }
        __syncthreads();   // gather done before x prologue overwrites
    }

    // ---- x prologue: rows hbase-1..hbase+4 -> slots 0..5 (1584 units) ----
    {
        float svp[4][8];
        #pragma unroll
        for (int k = 0; k < 4; ++k) {
            int u = tid + k * 512;
            if (u < 1584) {
                int g = u / 396, r = u - g * 396, hh = r / 66, ww = r - hh * 66;
                int row = hbase + hh - 1, cl = w0 + ww - 1;
                bool ok = ((unsigned)row < 512u) & ((unsigned)cl < 512u);
                int rowc = row < 0 ? 0 : (row > 511 ? 511 : row);
                int clc  = cl  < 0 ? 0 : (cl  > 511 ? 511 : cl);
                const float* src = xb + (size_t)(g * 8) * HW + rowc * WWD + clc;
                #pragma unroll
                for (int j = 0; j < 8; ++j) { float v = src[(size_t)j * HW]; svp[k][j] = ok ? v : 0.f; }
            }
        }
        #pragma unroll
        for (int k = 0; k < 4; ++k) {
            int u = tid + k * 512;
            if (u < 1584) {
                int g = u / 396, p = u - g * 396;   // p = hh*66+ww = slot*66+ww
                unsigned q0 = (unsigned)f2bf(svp[k][0]) | ((unsigned)f2bf(svp[k][1]) << 16);
                unsigned q1 = (unsigned)f2bf(svp[k][2]) | ((unsigned)f2bf(svp[k][3]) << 16);
                unsigned q2 = (unsigned)f2bf(svp[k][4]) | ((unsigned)f2bf(svp[k][5]) << 16);
                unsigned q3 = (unsigned)f2bf(svp[k][6]) | ((unsigned)f2bf(svp[k][7]) << 16);
                u32x4 q = { q0, q1, q2, q3 };
                *(u32x4*)(smem + (g * NPIX + p) * 16) = q;
            }
        }
    }

    float svA[3][8], svB[3][8];
    issue4(xb, hbase + 5, w0, svA);   // rows 5..8, repacked in body 0
    __builtin_amdgcn_sched_barrier(0);
    __syncthreads();                  // prologue-only full drain (svA lands too)

    int srb = 0;
    conv_body<1, 1, 1>(smem, xb, ob, wf, svA, svB, srb, hbase, hbase + 9, w0, wv, col16, g4);
    srb = 4;
    #pragma unroll 1
    for (int tp = 0; tp < 14; ++tp) {   // t = 1..28
        int t1 = 1 + 2 * tp;
        conv_body<1, 1, 1>(smem, xb, ob, wf, svB, svA, srb,
                           hbase + 4 * t1, hbase + 4 * t1 + 9, w0, wv, col16, g4);
        srb += 4; if (srb >= ROWS) srb -= ROWS;
        conv_body<1, 1, 1>(smem, xb, ob, wf, svA, svB, srb,
                           hbase + 4 * (t1 + 1), hbase + 4 * (t1 + 1) + 9, w0, wv, col16, g4);
        srb += 4; if (srb >= ROWS) srb -= ROWS;
    }
    // t = 29: issues rows 125..128 into svA
    conv_body<1, 1, 1>(smem, xb, ob, wf, svB, svA, srb, hbase + 116, hbase + 125, w0, wv, col16, g4);
    srb += 4; if (srb >= ROWS) srb -= ROWS;
    // t = 30: repack svA; no issue
    conv_body<1, 0, 1>(smem, xb, ob, wf, svA, svB, srb, hbase + 120, 0, w0, wv, col16, g4);
    srb += 4; if (srb >= ROWS) srb -= ROWS;
    // t = 31: compute only
    conv_body<0, 0, 0>(smem, xb, ob, wf, svB, svA, srb, hbase + 124, 0, w0, wv, col16, g4);
}

extern "C" void kernel_launch(void* const* d_in, const int* in_sizes, int n_in,
                              void* d_out, int out_size, void* d_ws, size_t ws_size,
                              hipStream_t stream) {
    const float* x  = (const float*)d_in[0];
    const float* wk = (const float*)d_in[1];
    float* out = (float*)d_out;
    dim3 grid(WWD / TW, HH / (4 * NITER), 16);   // (8, 4, 16) = 512 blocks, 2/CU
    conv3x3_mfma<<<grid, 512, 0, stream>>>(x, wk, out);
}

// Round 8
// 286.783 us; speedup vs baseline: 3.3424x; 3.3424x over previous
//
#include <hip/hip_runtime.h>
#include <hip/hip_bf16.h>

typedef __attribute__((ext_vector_type(8))) short bf16x8;
typedef __attribute__((ext_vector_type(4))) float f32x4;
typedef __attribute__((ext_vector_type(4))) unsigned int u32x4;

#define HH 512
#define WWD 512
#define HW (HH * WWD)
#define TW 64
#define SLOTS 6                  // circular row slots: 4 read + 2 write, disjoint
#define PXG (SLOTS * 66)         // 396 pixels per ic-group
#define XBYTES (4 * PXG * 16)    // 25344
#define WOFF XBYTES              // weights at 25344, 18432 B
#define DUMMY (WOFF + 18432)     // 43776: 1KB scratch for padded-decode dummies
#define NITER 32                 // 32 * 2 = 64 rows per block

__device__ __forceinline__ unsigned short f2bf(float f) {
    unsigned u = __builtin_bit_cast(unsigned, f);
    u += 0x7FFFu + ((u >> 16) & 1u);   // round-to-nearest-even
    return (unsigned short)(u >> 16);
}

// steady-state tile: 544 units = (g:4) x (hh:2) x (ww:68), real ww<66
__device__ __forceinline__ void issue2(const float* __restrict__ xb, int row0, int w0,
                                       float (&sv)[3][8]) {
    #pragma unroll
    for (int k = 0; k < 3; ++k) {
        if (k == 2 && threadIdx.x >= 32) continue;
        int u = (k < 2) ? (int)threadIdx.x + k * 256 : 512 + (int)threadIdx.x;
        int g = u / 136, r = u - g * 136, hh = r / 68, ww = r - hh * 68;
        int wwc = ww < 66 ? ww : 65;
        int row = row0 + hh, cl = w0 + wwc - 1;
        bool ok = (ww < 66) & ((unsigned)row < 512u) & ((unsigned)cl < 512u);
        int rowc = row < 0 ? 0 : (row > 511 ? 511 : row);
        int clc  = cl  < 0 ? 0 : (cl  > 511 ? 511 : cl);
        const float* src = xb + (size_t)(g * 8) * HW + rowc * WWD + clc;
        #pragma unroll
        for (int j = 0; j < 8; ++j) { float v = src[(size_t)j * HW]; sv[k][j] = ok ? v : 0.f; }
    }
}

__device__ __forceinline__ void write2(char* smem, int wsb, float (&sv)[3][8]) {
    #pragma unroll
    for (int k = 0; k < 3; ++k) {
        if (k == 2 && threadIdx.x >= 32) continue;
        int u = (k < 2) ? (int)threadIdx.x + k * 256 : 512 + (int)threadIdx.x;
        int g = u / 136, r = u - g * 136, hh = r / 68, ww = r - hh * 68;
        int slot = wsb + hh; if (slot >= SLOTS) slot -= SLOTS;
        int byte = (ww < 66) ? (g * PXG + slot * 66 + ww) * 16
                             : (DUMMY + (threadIdx.x & 63) * 16);
        unsigned q0 = (unsigned)f2bf(sv[k][0]) | ((unsigned)f2bf(sv[k][1]) << 16);
        unsigned q1 = (unsigned)f2bf(sv[k][2]) | ((unsigned)f2bf(sv[k][3]) << 16);
        unsigned q2 = (unsigned)f2bf(sv[k][4]) | ((unsigned)f2bf(sv[k][5]) << 16);
        unsigned q3 = (unsigned)f2bf(sv[k][6]) | ((unsigned)f2bf(sv[k][7]) << 16);
        u32x4 q = { q0, q1, q2, q3 };
        *(u32x4*)(smem + byte) = q;
    }
}

template<bool WR, bool ISS, bool BAR>
__device__ __forceinline__ void conv_body(char* smem, const float* __restrict__ xb,
                                          float* __restrict__ ob,
                                          float (&cur)[3][8], float (&nxt)[3][8],
                                          int srb, int rowbase, int issrow, int w0,
                                          int wv, int col16, int g4) {
    if (WR) {
        // per wave: 4 newest outstanding vmem = prev iter's stores; waiting to 4
        // retires cur's loads (issued before those stores) without draining stores.
        asm volatile("s_waitcnt vmcnt(4)" ::: "memory");
        __builtin_amdgcn_sched_barrier(0);
        int wsb = srb + 4; if (wsb >= SLOTS) wsb -= SLOTS;
        write2(smem, wsb, cur);
    }
    if (ISS) issue2(xb, issrow, w0, nxt);   // lands during next iter's compute

    f32x4 acc[2][2];
    {
        f32x4 z = {0.f, 0.f, 0.f, 0.f};
        acc[0][0] = z; acc[0][1] = z; acc[1][0] = z; acc[1][1] = z;
    }
    int rs[3];
    #pragma unroll
    for (int dh = 0; dh < 3; ++dh) {
        int s = srb + (wv & 1) + dh; if (s >= SLOTS) s -= SLOTS;
        rs[dh] = s * 66;
    }
    const int wcb = (wv >> 1) * 32;
    const char* xg = smem + g4 * (PXG * 16);
    const char* wg = smem + WOFF + g4 * 512 + col16 * 16;
    #pragma unroll
    for (int dh = 0; dh < 3; ++dh) {
        #pragma unroll
        for (int dw = 0; dw < 3; ++dw) {
            const int tap = dh * 3 + dw;
            bf16x8 b0 = *(const bf16x8*)(wg + tap * 2048);
            bf16x8 b1 = *(const bf16x8*)(wg + tap * 2048 + 256);
            #pragma unroll
            for (int m = 0; m < 2; ++m) {
                bf16x8 a = *(const bf16x8*)(xg + (rs[dh] + wcb + m * 16 + col16 + dw) * 16);
                acc[m][0] = __builtin_amdgcn_mfma_f32_16x16x32_bf16(a, b0, acc[m][0], 0, 0, 0);
                acc[m][1] = __builtin_amdgcn_mfma_f32_16x16x32_bf16(a, b1, acc[m][1], 0, 0, 0);
            }
        }
    }
    {
        float* orow = ob + (size_t)(rowbase + (wv & 1)) * WWD + w0 + wcb;
        #pragma unroll
        for (int m = 0; m < 2; ++m)
            #pragma unroll
            for (int n = 0; n < 2; ++n)
                *(f32x4*)(orow + (size_t)(n * 16 + col16) * HW + m * 16 + g4 * 4) = acc[m][n];
    }
    if (BAR) {
        asm volatile("s_waitcnt lgkmcnt(0)" ::: "memory");
        __builtin_amdgcn_sched_barrier(0);
        __builtin_amdgcn_s_barrier();
        __builtin_amdgcn_sched_barrier(0);
    }
}

__global__ __launch_bounds__(256, 3)
void conv3x3_mfma(const float* __restrict__ x,
                  const float* __restrict__ wk,
                  float* __restrict__ out) {
    __shared__ __align__(16) char smem[DUMMY + 1024];   // 44800 B -> 3 blocks/CU

    const int tid   = threadIdx.x;
    const int lane  = tid & 63;
    const int wv    = tid >> 6;        // 0..3
    const int col16 = lane & 15;
    const int g4    = lane >> 4;

    const int w0    = blockIdx.x * TW;
    const int hbase = blockIdx.y * (2 * NITER);   // 64 rows per block
    const int b     = blockIdx.z;

    const float* xb = x + (size_t)b * 32 * HW;
    float* ob = out + (size_t)b * 32 * HW;

    // ---- weights -> LDS bf16 direct, [tap][icg][oc] 16B units (conflict-free) ----
    {
        unsigned short* wl = (unsigned short*)(smem + WOFF);
        for (int i = tid; i < 9216; i += 256) {
            int oc = i / 288; int rem = i - oc * 288;
            int ic = rem / 9; int tap = rem - ic * 9;
            wl[((tap * 4 + (ic >> 3)) * 32 + oc) * 8 + (ic & 7)] = f2bf(wk[i]);
        }
    }

    // ---- x prologue: rows hbase-1..hbase+2 -> slots 0..3 (1056 units) ----
    {
        float svp[5][8];
        #pragma unroll
        for (int k = 0; k < 5; ++k) {
            if (k == 4 && tid >= 32) continue;
            int u = (k < 4) ? tid + k * 256 : 1024 + tid;
            int g = u / 264, p = u - g * 264, hh = p / 66, ww = p - hh * 66;
            int row = hbase + hh - 1, cl = w0 + ww - 1;
            bool ok = ((unsigned)row < 512u) & ((unsigned)cl < 512u);
            int rowc = row < 0 ? 0 : (row > 511 ? 511 : row);
            int clc  = cl  < 0 ? 0 : (cl  > 511 ? 511 : cl);
            const float* src = xb + (size_t)(g * 8) * HW + rowc * WWD + clc;
            #pragma unroll
            for (int j = 0; j < 8; ++j) { float v = src[(size_t)j * HW]; svp[k][j] = ok ? v : 0.f; }
        }
        #pragma unroll
        for (int k = 0; k < 5; ++k) {
            if (k == 4 && tid >= 32) continue;
            int u = (k < 4) ? tid + k * 256 : 1024 + tid;
            int g = u / 264, p = u - g * 264;    // p = hh*66+ww, slot = hh directly
            unsigned q0 = (unsigned)f2bf(svp[k][0]) | ((unsigned)f2bf(svp[k][1]) << 16);
            unsigned q1 = (unsigned)f2bf(svp[k][2]) | ((unsigned)f2bf(svp[k][3]) << 16);
            unsigned q2 = (unsigned)f2bf(svp[k][4]) | ((unsigned)f2bf(svp[k][5]) << 16);
            unsigned q3 = (unsigned)f2bf(svp[k][6]) | ((unsigned)f2bf(svp[k][7]) << 16);
            u32x4 q = { q0, q1, q2, q3 };
            *(u32x4*)(smem + (g * PXG + p) * 16) = q;
        }
    }

    float svA[3][8], svB[3][8];
    issue2(xb, hbase + 3, w0, svA);   // rows hbase+3,4 (rrel 4,5), written at t=0
    __builtin_amdgcn_sched_barrier(0);
    __syncthreads();                  // prologue-only full drain (svA lands too)

    int srb = 0;
    // t = 0
    conv_body<1, 1, 1>(smem, xb, ob, svA, svB, 0, hbase, hbase + 5, w0, wv, col16, g4);
    srb = 2;
    #pragma unroll 1
    for (int tp = 0; tp < 14; ++tp) {   // t = 1..28
        int t1 = 1 + 2 * tp;
        conv_body<1, 1, 1>(smem, xb, ob, svB, svA, srb,
                           hbase + 2 * t1, hbase + 2 * t1 + 5, w0, wv, col16, g4);
        srb += 2; if (srb >= SLOTS) srb -= SLOTS;
        conv_body<1, 1, 1>(smem, xb, ob, svA, svB, srb,
                           hbase + 2 * (t1 + 1), hbase + 2 * (t1 + 1) + 5, w0, wv, col16, g4);
        srb += 2; if (srb >= SLOTS) srb -= SLOTS;
    }
    // t = 29: issues rows hbase+63,64 (rrel 64,65) into svA
    conv_body<1, 1, 1>(smem, xb, ob, svB, svA, srb, hbase + 58, hbase + 63, w0, wv, col16, g4);
    srb += 2; if (srb >= SLOTS) srb -= SLOTS;
    // t = 30: write svA; no issue
    conv_body<1, 0, 1>(smem, xb, ob, svA, svB, srb, hbase + 60, 0, w0, wv, col16, g4);
    srb += 2; if (srb >= SLOTS) srb -= SLOTS;
    // t = 31: compute only
    conv_body<0, 0, 0>(smem, xb, ob, svB, svA, srb, hbase + 62, 0, w0, wv, col16, g4);
}

extern "C" void kernel_launch(void* const* d_in, const int* in_sizes, int n_in,
                              void* d_out, int out_size, void* d_ws, size_t ws_size,
                              hipStream_t stream) {
    const float* x  = (const float*)d_in[0];
    const float* wk = (const float*)d_in[1];
    float* out = (float*)d_out;
    dim3 grid(WWD / TW, HH / (2 * NITER), 16);   // (8, 8, 16) = 1024 blocks, 3/CU resident
    conv3x3_mfma<<<grid, 256, 0, stream>>>(x, wk, out);
}

// Round 9
// 273.519 us; speedup vs baseline: 3.5045x; 1.0485x over previous
//
#include <hip/hip_runtime.h>
#include <hip/hip_bf16.h>

typedef __attribute__((ext_vector_type(8))) short bf16x8;
typedef __attribute__((ext_vector_type(4))) float f32x4;
typedef __attribute__((ext_vector_type(4))) unsigned int u32x4;

#define HW (512 * 512)
#define TW 64
#define SLOTS 6                  // tile row slots: 4 read + 2 write, disjoint
#define PXG (SLOTS * 66)         // 396 pixels per ic-group
#define TILE_B (4 * PXG * 16)    // 25344: bf16 [g][pixel] MFMA tile
#define STAGE_HALF 20480         // f32 stage: 32ch x 2row x 288B = 18432, pad to 5x1024x4waves
#define SREAL 18432
#define DUMMY (TILE_B + 2 * STAGE_HALF)   // 66304
#define NITER 32

#define SCHED() __builtin_amdgcn_sched_barrier(0)

__device__ __forceinline__ unsigned short f2bf(float f) {
    unsigned u = __builtin_bit_cast(unsigned, f);
    u += 0x7FFFu + ((u >> 16) & 1u);   // RNE
    return (unsigned short)(u >> 16);
}

__device__ __forceinline__ void gll16(const float* g, char* l) {
    __builtin_amdgcn_global_load_lds(
        (const __attribute__((address_space(1))) void*)g,
        (__attribute__((address_space(3))) void*)l, 16, 0, 0);
}

// issue one stage tile (x rows row0, row0+1) into stage half `half`.
// 20 instrs/block, 5 per wave (uniform -> exact per-wave vmcnt).
// stage layout: [ch:32][hh:2][72 f32], window cols w0-4 .. w0+67 (16B-aligned).
__device__ __forceinline__ void issue_stage(const float* __restrict__ xb, int row0,
                                            int w0, char* smem, int half, int wvu) {
    const int lane = (int)threadIdx.x & 63;
    char* base = smem + TILE_B + half * STAGE_HALF;
    #pragma unroll
    for (int i = 0; i < 5; ++i) {
        int ob = (wvu * 5 + i) * 1024;
        int o  = ob + lane * 16;
        int o2 = o < (SREAL - 1) ? o : (SREAL - 1);   // pad instrs -> harmless clamp
        int ch = o2 / 576;
        int rem = o2 - ch * 576;
        int hh = rem / 288;
        int wl = (rem - hh * 288) >> 2;               // 0..71 (mult of 4 for real lanes)
        int row = row0 + hh; row = row < 511 ? row : 511;
        int cb = w0 - 4 + wl;
        cb = cb < 0 ? 0 : (cb > 508 ? 508 : cb);      // stays 16B-aligned
        gll16(xb + (size_t)ch * HW + row * 512 + cb, base + ob);
    }
}

template<bool TRANS, bool GLL, bool BAR>
__device__ __forceinline__ void body(char* smem, const float* __restrict__ xb,
                                     float* __restrict__ ob, bf16x8 (&wf)[9][2],
                                     int srb, int half, int rowbase, int w0,
                                     int wv, int wvu, int col16, int g4) {
    // ---- issue loads for t+1 (other stage half; in flight across the barrier) ----
    if (GLL) issue_stage(xb, rowbase + 5, w0, smem, half ^ 1, wvu);

    // ---- transpose+convert stage[half] (x rows rowbase+3, +4) -> tile slots srb+4,srb+5 ----
    if (TRANS) {
        const char* sb = smem + TILE_B + half * STAGE_HALF;
        const int rowA = rowbase + 3;
        #pragma unroll
        for (int k = 0; k < 3; ++k) {
            if (k == 2 && threadIdx.x >= 32) continue;
            int u = (k < 2) ? (int)threadIdx.x + k * 256 : 512 + (int)threadIdx.x;
            int g = u / 136, r = u - g * 136, sl = r / 68, ww = r - sl * 68;
            float v[8];
            int ba = g * 8 * 576 + sl * 288 + (ww + 3) * 4;
            #pragma unroll
            for (int j = 0; j < 8; ++j) v[j] = *(const float*)(sb + ba + j * 576);
            bool ok = (ww < 66) & ((unsigned)(w0 + ww - 1) < 512u) & (rowA + sl < 512);
            #pragma unroll
            for (int j = 0; j < 8; ++j) v[j] = ok ? v[j] : 0.f;
            unsigned q0 = (unsigned)f2bf(v[0]) | ((unsigned)f2bf(v[1]) << 16);
            unsigned q1 = (unsigned)f2bf(v[2]) | ((unsigned)f2bf(v[3]) << 16);
            unsigned q2 = (unsigned)f2bf(v[4]) | ((unsigned)f2bf(v[5]) << 16);
            unsigned q3 = (unsigned)f2bf(v[6]) | ((unsigned)f2bf(v[7]) << 16);
            int slot = srb + 4 + sl; if (slot >= SLOTS) slot -= SLOTS;
            int byte = (ww < 66) ? (g * PXG + slot * 66 + ww) * 16
                                 : (DUMMY + ((int)threadIdx.x & 63) * 16);
            u32x4 q = { q0, q1, q2, q3 };
            *(u32x4*)(smem + byte) = q;
        }
    }

    // ---- compute: output rows rowbase+(wv&1), w-half (wv>>1) ----
    f32x4 acc[2][2];
    {
        f32x4 z = {0.f, 0.f, 0.f, 0.f};
        acc[0][0] = z; acc[0][1] = z; acc[1][0] = z; acc[1][1] = z;
    }
    int rs[3];
    #pragma unroll
    for (int dh = 0; dh < 3; ++dh) {
        int s = srb + (wv & 1) + dh; if (s >= SLOTS) s -= SLOTS;
        rs[dh] = s * 66;
    }
    const int wcb = (wv >> 1) * 32;
    const char* xg = smem + g4 * (PXG * 16);
    #pragma unroll
    for (int dh = 0; dh < 3; ++dh) {
        #pragma unroll
        for (int dw = 0; dw < 3; ++dw) {
            const int tap = dh * 3 + dw;
            #pragma unroll
            for (int m = 0; m < 2; ++m) {
                bf16x8 a = *(const bf16x8*)(xg + (rs[dh] + wcb + m * 16 + col16 + dw) * 16);
                acc[m][0] = __builtin_amdgcn_mfma_f32_16x16x32_bf16(a, wf[tap][0], acc[m][0], 0, 0, 0);
                acc[m][1] = __builtin_amdgcn_mfma_f32_16x16x32_bf16(a, wf[tap][1], acc[m][1], 0, 0, 0);
            }
        }
    }
    {
        float* orow = ob + (size_t)(rowbase + (wv & 1)) * 512 + w0 + wcb;
        #pragma unroll
        for (int m = 0; m < 2; ++m)
            #pragma unroll
            for (int n = 0; n < 2; ++n)
                *(f32x4*)(orow + (size_t)(n * 16 + col16) * HW + m * 16 + g4 * 4) = acc[m][n];
    }

    if (BAR) {
        // drain gll(t+1) (per-wave exact); keep this iter's 4 stores in flight
        asm volatile("s_waitcnt vmcnt(4)" ::: "memory");
        SCHED();
        asm volatile("s_waitcnt lgkmcnt(0)" ::: "memory");
        SCHED();
        __builtin_amdgcn_s_barrier();
        SCHED();
    }
}

__global__ __launch_bounds__(256, 2)
void conv3x3_mfma(const float* __restrict__ x,
                  const float* __restrict__ wk,
                  float* __restrict__ out) {
    __shared__ __align__(16) char smem[DUMMY + 1024];   // 67328 B -> 2 blocks/CU

    const int tid   = (int)threadIdx.x;
    const int lane  = tid & 63;
    const int wv    = tid >> 6;
    const int wvu   = __builtin_amdgcn_readfirstlane(wv);
    const int col16 = lane & 15;
    const int g4    = lane >> 4;

    const int w0    = blockIdx.x * TW;
    const int hbase = blockIdx.y * 64;
    const int b     = blockIdx.z;

    const float* xb = x + (size_t)b * 32 * HW;
    float* ob = out + (size_t)b * 32 * HW;

    // ---- prologue 1: weights f32 -> scratch (stage region) ----
    {
        float* ws = (float*)(smem + TILE_B);   // 36992 B <= 40960
        for (int i = tid; i < 9216; i += 256) {
            int oc = i / 288;
            ws[oc * 289 + (i - oc * 288)] = wk[i];
        }
    }
    // ---- prologue 2: x rows hbase-1..hbase+2 -> regs (1056 units) ----
    float svp[5][8];
    #pragma unroll
    for (int k = 0; k < 5; ++k) {
        if (k == 4 && tid >= 32) continue;
        int u = (k < 4) ? tid + k * 256 : 1024 + tid;
        int g = u / 264, p = u - g * 264, hh = p / 66, ww = p - hh * 66;
        int row = hbase + hh - 1, cl = w0 + ww - 1;
        bool ok = ((unsigned)row < 512u) & ((unsigned)cl < 512u);
        int rowc = row < 0 ? 0 : (row > 511 ? 511 : row);
        int clc  = cl  < 0 ? 0 : (cl  > 511 ? 511 : cl);
        const float* src = xb + (size_t)(g * 8) * HW + rowc * 512 + clc;
        #pragma unroll
        for (int j = 0; j < 8; ++j) { float v = src[(size_t)j * HW]; svp[k][j] = ok ? v : 0.f; }
    }
    __syncthreads();   // weights scratch visible

    // ---- prologue 3: gather weight fragments to registers ----
    bf16x8 wf[9][2];
    {
        const float* ws = (const float*)(smem + TILE_B);
        #pragma unroll
        for (int tap = 0; tap < 9; ++tap) {
            #pragma unroll
            for (int n = 0; n < 2; ++n) {
                bf16x8 f;
                #pragma unroll
                for (int j = 0; j < 8; ++j)
                    f[j] = (short)f2bf(ws[(n * 16 + col16) * 289 + (g4 * 8 + j) * 9 + tap]);
                wf[tap][n] = f;
            }
        }
    }
    __syncthreads();   // scratch free before gll writes stage

    // ---- prologue 4: write tile slots 0..3; issue stage L(0) (rows 3,4) ----
    #pragma unroll
    for (int k = 0; k < 5; ++k) {
        if (k == 4 && tid >= 32) continue;
        int u = (k < 4) ? tid + k * 256 : 1024 + tid;
        int g = u / 264, p = u - g * 264;       // p = slot*66+ww directly
        unsigned q0 = (unsigned)f2bf(svp[k][0]) | ((unsigned)f2bf(svp[k][1]) << 16);
        unsigned q1 = (unsigned)f2bf(svp[k][2]) | ((unsigned)f2bf(svp[k][3]) << 16);
        unsigned q2 = (unsigned)f2bf(svp[k][4]) | ((unsigned)f2bf(svp[k][5]) << 16);
        unsigned q3 = (unsigned)f2bf(svp[k][6]) | ((unsigned)f2bf(svp[k][7]) << 16);
        u32x4 q = { q0, q1, q2, q3 };
        *(u32x4*)(smem + (g * PXG + p) * 16) = q;
    }
    issue_stage(xb, hbase + 3, w0, smem, 0, wvu);
    __syncthreads();   // full drain: tile 0..3 + stage half 0 ready

    int srb = 0;
    #pragma unroll 1
    for (int t = 0; t < 30; ++t) {
        body<1, 1, 1>(smem, xb, ob, wf, srb, t & 1, hbase + 2 * t, w0, wv, wvu, col16, g4);
        srb += 2; if (srb >= SLOTS) srb -= SLOTS;
    }
    // t = 30: transpose stage[0] (rows 63,64); no new loads
    body<1, 0, 1>(smem, xb, ob, wf, srb, 0, hbase + 60, w0, wv, wvu, col16, g4);
    srb += 2; if (srb >= SLOTS) srb -= SLOTS;
    // t = 31: compute only
    body<0, 0, 0>(smem, xb, ob, wf, srb, 1, hbase + 62, w0, wv, wvu, col16, g4);
}

extern "C" void kernel_launch(void* const* d_in, const int* in_sizes, int n_in,
                              void* d_out, int out_size, void* d_ws, size_t ws_size,
                              hipStream_t stream) {
    const float* x  = (const float*)d_in[0];
    const float* wk = (const float*)d_in[1];
    float* out = (float*)d_out;
    dim3 grid(512 / TW, 512 / 64, 16);   // (8, 8, 16) = 1024 blocks
    conv3x3_mfma<<<grid, 256, 0, stream>>>(x, wk, out);
}